// Round 3
// baseline (841.500 us; speedup 1.0000x reference)
//
#include <hip/hip_runtime.h>

// Swin window attention, fused one-kernel-per-window design. Round 3:
// R2's occupancy restructure (52.4KB LDS => 3 blocks/CU) with the s_vt
// corruption fixed: V^T stride back to 72 with pad tokens >=49 explicitly
// zeroed (R2's stride-56 layout made each channel's token 56..63 writes
// clobber the next channel's tokens 0..7 -- a cross-wave race).
// s_k shrunk to 49 rows instead (pad K rows are masked to -inf anyway):
// writes guarded m<49, reads clamped min(row,48) (clamped lanes broadcast).
//   - x A-frags loaded directly from global (rows are contiguous 768B)
//   - wave w computes its own 16-row M-tile for ALL 192 cols of Q/K/V
//     => Q never touches LDS (kept as packed C-frags in 24 VGPRs)
//   - P/Q/O fragment-layout bounces via 1.28KB per-wave scratch
//   - ONE __syncthreads total (after K/V^T stores)
// Shapes: B=64, RES=56, DIMS=192, HEADS=6, HD=32, WS=7, N=49, nW=64, SHIFT=3.
//
// MFMA 16x16x32 bf16 layouts:
//   A-frag: lane holds A[m=lane&15][k=(lane>>4)*8+j]  (16B contig)
//   B-frag: lane holds B[k=(lane>>4)*8+j][n=lane&15]
//   C/D   : lane holds D[m=(lane>>4)*4+r][n=lane&15]
// Mask quirk: reference repeats mask by batch (scores[b*64+w] gets mask[b]).

typedef __attribute__((ext_vector_type(8))) short bf16x8;
typedef __attribute__((ext_vector_type(4))) short short4v;
typedef __attribute__((ext_vector_type(4))) float f32x4;

__device__ __forceinline__ short f2bf(float x) {
  unsigned u = __builtin_bit_cast(unsigned, x);
  u += 0x7fffu + ((u >> 16) & 1u);   // RNE
  return (short)(u >> 16);
}

// ---------------- prep: weight transpose->bf16, bias expansion ----------------
__global__ void prep_kernel(const float* __restrict__ wq, const float* __restrict__ wk,
                            const float* __restrict__ wv, const float* __restrict__ wo,
                            const float* __restrict__ table,
                            short* __restrict__ wT, float* __restrict__ biasx) {
  int tid = blockIdx.x * 256 + threadIdx.x;
  if (tid < 4 * 36864) {
    int mat = tid / 36864, rem = tid % 36864;
    int k = rem / 192, n = rem % 192;
    const float* w = (mat == 0) ? wq : (mat == 1) ? wk : (mat == 2) ? wv : wo;
    wT[mat * 36864 + n * 192 + k] = f2bf(w[k * 192 + n]);
  }
  if (tid < 6 * 2401) {
    int h = tid / 2401, rem = tid % 2401;
    int q = rem / 49, k = rem % 49;
    int idx = ((q / 7) - (k / 7) + 6) * 13 + ((q % 7) - (k % 7) + 6);
    biasx[tid] = table[idx * 6 + h];
  }
}

// ---------------- main fused kernel ----------------
#define SKS 200   // s_k row stride (shorts): 400B -> rows spread over banks
#define VTS 72    // s_vt row stride (shorts): 144B; holds 64 tokens, no overflow
#define SCS 40    // scratch row stride (shorts): 80B

__launch_bounds__(256, 3)
__global__ void swin_attn_kernel(const float* __restrict__ x,
                                 const short* __restrict__ wT,
                                 const float* __restrict__ biasx,
                                 const float* __restrict__ bq, const float* __restrict__ bk,
                                 const float* __restrict__ bv, const float* __restrict__ bo,
                                 float* __restrict__ out) {
  __shared__ short s_k[49 * SKS];       // 19,600 B  K row-major, rows 0..48 only
  __shared__ short s_vt[192 * VTS];     // 27,648 B  V transposed [chan][token]
  __shared__ short s_scr[4][16 * SCS];  //  5,120 B  per-wave bounce scratch
  // total 52,368 B -> 3 blocks/CU

  const int tid  = threadIdx.x;
  const int w    = tid >> 6;       // wave id 0..3 (owns query rows 16w..16w+15)
  const int lane = tid & 63;
  const int quad = lane >> 4;
  const int l15  = lane & 15;
  short* scr = s_scr[w];

  const int bw  = blockIdx.x;
  const int b   = bw >> 6;                 // batch
  const int wi  = bw & 63;                 // window in image
  const int wwh = wi >> 3, www = wi & 7;   // spatial window coords
  const int mwh = b >> 3,  mww = b & 7;    // mask window coords (reference quirk!)

  // ---- x A-frags for m-tile w, straight from global (row = 768B contiguous) ----
  const int mload = min(w * 16 + l15, 48);   // clamp pad rows (finite clone of 48)
  int lth = mload / 7, ltw = mload - lth * 7;
  int lgh = wwh * 7 + lth + 3; if (lgh >= 56) lgh -= 56;
  int lgw = www * 7 + ltw + 3; if (lgw >= 56) lgw -= 56;
  const float* xrow = x + (((b * 56 + lgh) * 56 + lgw) * 192) + quad * 8;
  bf16x8 axw[6];
#pragma unroll
  for (int ks = 0; ks < 6; ++ks) {
    const float4 v0 = *(const float4*)(xrow + ks * 32);
    const float4 v1 = *(const float4*)(xrow + ks * 32 + 4);
    bf16x8 a;
    a[0] = f2bf(v0.x); a[1] = f2bf(v0.y); a[2] = f2bf(v0.z); a[3] = f2bf(v0.w);
    a[4] = f2bf(v1.x); a[5] = f2bf(v1.y); a[6] = f2bf(v1.z); a[7] = f2bf(v1.w);
    axw[ks] = a;
  }

  const f32x4 zero4 = {0.f, 0.f, 0.f, 0.f};
  short4v qc[12];   // Q C-frags, packed bf16 (rows 16w+quad*4+r, col j*16+l15)

  // ---- QKV projection: m-tile w x all 192 cols ----
#pragma unroll
  for (int mat = 0; mat < 3; ++mat) {
    const short* wt = wT + mat * 36864;
    const float* bias = (mat == 0) ? bq : (mat == 1) ? bk : bv;
#pragma unroll
    for (int j = 0; j < 12; ++j) {
      const int col = j * 16 + l15;
      f32x4 acc = zero4;
#pragma unroll
      for (int ks = 0; ks < 6; ++ks) {
        bf16x8 bfr = *(const bf16x8*)(wt + col * 192 + ks * 32 + quad * 8);
        acc = __builtin_amdgcn_mfma_f32_16x16x32_bf16(axw[ks], bfr, acc, 0, 0, 0);
      }
      const float bb = bias[col];
      if (mat == 0) {
        short4v qv;
#pragma unroll
        for (int r = 0; r < 4; ++r) qv[r] = f2bf(acc[r] + bb);
        qc[j] = qv;
      } else if (mat == 1) {
#pragma unroll
        for (int r = 0; r < 4; ++r) {
          int m = w * 16 + quad * 4 + r;
          if (m < 49) s_k[m * SKS + col] = f2bf(acc[r] + bb);  // rows 49+ not stored
        }
      } else {
        short4v vv;
#pragma unroll
        for (int r = 0; r < 4; ++r) {
          int m = w * 16 + quad * 4 + r;
          vv[r] = (m < 49) ? f2bf(acc[r] + bb) : (short)0;  // zero pad tokens: P=0 x finite
        }
        *(short4v*)(s_vt + col * VTS + w * 16 + quad * 4) = vv;   // 8B aligned
      }
    }
  }
  __syncthreads();   // the only barrier: K/V^T visible to all waves

  // ---- attention: wave w owns query rows 16w..16w+15 ----
  int cm[4], mbias[4];
#pragma unroll
  for (int r = 0; r < 4; ++r) {
    int m = w * 16 + quad * 4 + r;
    int mm = (m < 49) ? m : 48;
    mbias[r] = mm * 49;
    int th = mm / 7, tw = mm - th * 7;
    int ch = (mwh == 7) ? (1 + (th >= 4)) : 0;
    int cw = (mww == 7) ? (1 + (tw >= 4)) : 0;
    cm[r] = ch * 3 + cw;
  }
  int cn[4], nclamp[4], nvalid[4], krow[4];
#pragma unroll
  for (int nt = 0; nt < 4; ++nt) {
    int n = nt * 16 + l15;
    nvalid[nt] = (n < 49);
    int nn = nvalid[nt] ? n : 48;
    nclamp[nt] = nn;
    krow[nt] = nn * SKS;   // clamped K row (clamped lanes broadcast-read row 48)
    int th = nn / 7, tw = nn - th * 7;
    int ch = (mwh == 7) ? (1 + (th >= 4)) : 0;
    int cw = (mww == 7) ? (1 + (tw >= 4)) : 0;
    cn[nt] = ch * 3 + cw;
  }

  const float SCALE = 0.17677669529663687f;  // 1/sqrt(32)
  const float NEGINF = -__builtin_inff();
  bf16x8 ao[6];   // O A-frags for the out-projection, built per head

  for (int h = 0; h < 6; ++h) {
    const int d0 = h * 32;
    const float* bx = biasx + h * 2401;

    // Q: C-frag -> A-frag bounce through per-wave scratch (same-wave ordered)
#pragma unroll
    for (int jj = 0; jj < 2; ++jj) {
      short4v qv = qc[2 * h + jj];
#pragma unroll
      for (int r = 0; r < 4; ++r)
        scr[(quad * 4 + r) * SCS + jj * 16 + l15] = qv[r];
    }
    bf16x8 qf = *(const bf16x8*)(scr + l15 * SCS + quad * 8);

    float sv[4][4];
#pragma unroll
    for (int nt = 0; nt < 4; ++nt) {
      bf16x8 kf = *(const bf16x8*)(s_k + krow[nt] + d0 + quad * 8);
      f32x4 sfr = __builtin_amdgcn_mfma_f32_16x16x32_bf16(qf, kf, zero4, 0, 0, 0);
#pragma unroll
      for (int r = 0; r < 4; ++r) {
        float v = sfr[r] * SCALE + bx[mbias[r] + nclamp[nt]]
                + ((cm[r] == cn[nt]) ? 0.f : -1000.f);
        sv[nt][r] = nvalid[nt] ? v : NEGINF;
      }
    }
    // row softmax across nt x 16 lanes of the quad
    float inv[4];
#pragma unroll
    for (int r = 0; r < 4; ++r) {
      float mx = fmaxf(fmaxf(sv[0][r], sv[1][r]), fmaxf(sv[2][r], sv[3][r]));
#pragma unroll
      for (int d = 1; d < 16; d <<= 1) mx = fmaxf(mx, __shfl_xor(mx, d));
      float s0 = 0.f;
#pragma unroll
      for (int nt = 0; nt < 4; ++nt) {
        float e = __expf(sv[nt][r] - mx);
        sv[nt][r] = e;
        s0 += e;
      }
#pragma unroll
      for (int d = 1; d < 16; d <<= 1) s0 += __shfl_xor(s0, d);
      inv[r] = 1.0f / s0;   // normalization folded into O epilogue
    }

    // PV in two 32-wide k halves; P bounced C->A through scratch each half
    f32x4 of[2] = {zero4, zero4};
#pragma unroll
    for (int half = 0; half < 2; ++half) {
#pragma unroll
      for (int jj = 0; jj < 2; ++jj)
#pragma unroll
        for (int r = 0; r < 4; ++r)
          scr[(quad * 4 + r) * SCS + jj * 16 + l15] = f2bf(sv[half * 2 + jj][r]);
      bf16x8 pf = *(const bf16x8*)(scr + l15 * SCS + quad * 8);
#pragma unroll
      for (int nt2 = 0; nt2 < 2; ++nt2) {
        bf16x8 vf = *(const bf16x8*)(s_vt + (d0 + nt2 * 16 + l15) * VTS + half * 32 + quad * 8);
        of[nt2] = __builtin_amdgcn_mfma_f32_16x16x32_bf16(pf, vf, of[nt2], 0, 0, 0);
      }
    }

    // O: normalize, C-frag -> A-frag bounce; head h == k-chunk h of out-proj
#pragma unroll
    for (int nt2 = 0; nt2 < 2; ++nt2)
#pragma unroll
      for (int r = 0; r < 4; ++r)
        scr[(quad * 4 + r) * SCS + nt2 * 16 + l15] = f2bf(of[nt2][r] * inv[r]);
    ao[h] = *(const bf16x8*)(scr + l15 * SCS + quad * 8);
  }

  // ---- output projection + windowed store (own 16 rows, all 192 cols) ----
  int rowbase[4], rvalid[4];
#pragma unroll
  for (int r = 0; r < 4; ++r) {
    int m = w * 16 + quad * 4 + r;
    rvalid[r] = (m < 49);
    int mm = rvalid[r] ? m : 0;
    int th = mm / 7, tw = mm - th * 7;
    int gh = wwh * 7 + th + 3; if (gh >= 56) gh -= 56;
    int gw = www * 7 + tw + 3; if (gw >= 56) gw -= 56;
    rowbase[r] = ((b * 56 + gh) * 56 + gw) * 192;
  }

  const short* wto = wT + 3 * 36864;
#pragma unroll
  for (int nt = 0; nt < 12; ++nt) {
    const int col = nt * 16 + l15;
    f32x4 acc = zero4;
#pragma unroll
    for (int ks = 0; ks < 6; ++ks) {
      bf16x8 bfr = *(const bf16x8*)(wto + col * 192 + ks * 32 + quad * 8);
      acc = __builtin_amdgcn_mfma_f32_16x16x32_bf16(ao[ks], bfr, acc, 0, 0, 0);
    }
    const float bo_ = bo[col];
#pragma unroll
    for (int r = 0; r < 4; ++r)
      if (rvalid[r]) out[rowbase[r] + col] = acc[r] + bo_;
  }
}

extern "C" void kernel_launch(void* const* d_in, const int* in_sizes, int n_in,
                              void* d_out, int out_size, void* d_ws, size_t ws_size,
                              hipStream_t stream) {
  const float* x     = (const float*)d_in[0];
  const float* table = (const float*)d_in[1];
  const float* wq    = (const float*)d_in[2];
  const float* bq    = (const float*)d_in[3];
  const float* wk    = (const float*)d_in[4];
  const float* bk    = (const float*)d_in[5];
  const float* wv    = (const float*)d_in[6];
  const float* bv    = (const float*)d_in[7];
  const float* wo    = (const float*)d_in[8];
  const float* bo    = (const float*)d_in[9];
  float* out = (float*)d_out;

  short* wT    = (short*)d_ws;                       // 294,912 B
  float* biasx = (float*)((char*)d_ws + 294912);     //  57,624 B

  prep_kernel<<<576, 256, 0, stream>>>(wq, wk, wv, wo, table, wT, biasx);
  swin_attn_kernel<<<4096, 256, 0, stream>>>(x, wT, biasx, bq, bk, bv, bo, out);
}